// Round 4
// baseline (162.276 us; speedup 1.0000x reference)
//
#include <hip/hip_runtime.h>
#include <stdint.h>

// out[65536,64] = xa[65536,256] @ wa[256,64] + xb[65536,256] @ wb[256,64]
// Tall-skinny GEMM M=65536, N=64, K=512. Memory/latency-bound.
// R2/R3: x -> registers via depth-4 rotating prefetch (no x-LDS, no barriers
// in loop, compiler-counted vmcnt); weights in 64KB LDS in fragment-native
// lane-ordered layout (conflict-free 1KB wave reads); 2 blocks/CU = 16
// waves/CU for TLP.

#define WT_SHORTS (512 * 64)       // 32768 bf16
#define WT_BYTES  (WT_SHORTS * 2)  // 65536 B

typedef __bf16 bf16x8 __attribute__((ext_vector_type(8)));
typedef float  f32x4  __attribute__((ext_vector_type(4)));

// Fragment-native weight layout:
//   wt[((s*4 + cb)*64 + lane)*8 + j] = W[k][col]
//   with k = s*32 + (lane>>4)*8 + j   (k in [0,512): 0-255 -> wa, 256-511 -> wb)
//        col = (lane&15) + cb*16
// A wave's B-fragment read for (s,cb) is wlds + (s*4+cb)*1024 + lane*16:
// 64 lanes x 16B = contiguous 1KB -> zero bank conflicts.
__global__ void prep_wt_kernel(const float* __restrict__ wa,
                               const float* __restrict__ wb,
                               __bf16* __restrict__ wt) {
    int o2 = blockIdx.x * 256 + threadIdx.x;   // 0..16383, 2 outputs each
    #pragma unroll
    for (int h = 0; h < 2; ++h) {
        int o    = o2 * 2 + h;                 // 0..32767
        int j    = o & 7;
        int lane = (o >> 3) & 63;
        int cb   = (o >> 9) & 3;
        int s    = o >> 11;
        int k    = s * 32 + (lane >> 4) * 8 + j;
        int col  = (lane & 15) + cb * 16;
        float v  = (k < 256) ? wa[k * 64 + col] : wb[(k - 256) * 64 + col];
        wt[o] = (__bf16)v;
    }
}

template <bool USE_WS>
__global__ __launch_bounds__(512, 4)
void agg_gemm_kernel(const float* __restrict__ xa,
                     const float* __restrict__ xb,
                     const float* __restrict__ wa,
                     const float* __restrict__ wb,
                     const __bf16* __restrict__ wt,
                     float* __restrict__ out) {
    __shared__ __align__(16) __bf16 wlds[WT_SHORTS];   // 64 KB only -> 2 blocks/CU

    const int t    = threadIdx.x;
    const int lane = t & 63;
    const int wave = t >> 6;

    if (USE_WS) {
        // 64KB global->LDS, linear: 4096 f32x4 over 512 threads = 8 each
        const f32x4* g = (const f32x4*)wt;
        f32x4*       l = (f32x4*)&wlds[0];
        #pragma unroll
        for (int it = 0; it < 8; ++it)
            l[it * 512 + t] = g[it * 512 + t];
    } else {
        // fallback: build fragment-native layout straight from wa/wb
        for (int i = 0; i < 64; ++i) {
            int o    = t * 64 + i;
            int j    = o & 7;
            int ln   = (o >> 3) & 63;
            int cb   = (o >> 9) & 3;
            int s    = o >> 11;
            int k    = s * 32 + (ln >> 4) * 8 + j;
            int col  = (ln & 15) + cb * 16;
            wlds[o] = (__bf16)((k < 256) ? wa[k * 64 + col] : wb[(k - 256) * 64 + col]);
        }
    }
    __syncthreads();

    const int gw   = blockIdx.x * 8 + wave;   // tile id 0..4095
    const int tile = gw * 16;
    const int row  = lane & 15;               // A-row / D-col
    const int kg   = lane >> 4;               // 0..3

    const float* prow_a = xa + (size_t)(tile + row) * 256 + kg * 8;
    const float* prow_b = xb + (size_t)(tile + row) * 256 + kg * 8;

    // depth-4 rotating prefetch: per step this lane needs 8 consecutive
    // floats x[row][s*32 + kg*8 .. +7] = two f32x4.
    f32x4 xr[4][2];
    #pragma unroll
    for (int s = 0; s < 4; ++s) {
        xr[s][0] = *(const f32x4*)(prow_a + s * 32);
        xr[s][1] = *(const f32x4*)(prow_a + s * 32 + 4);
    }

    f32x4 acc0 = {0.f, 0.f, 0.f, 0.f};
    f32x4 acc1 = acc0, acc2 = acc0, acc3 = acc0;

    #pragma unroll
    for (int s = 0; s < 16; ++s) {
        f32x4 x0 = xr[s & 3][0];
        f32x4 x1 = xr[s & 3][1];

        // prefetch step s+4 into the slot just freed (static idx after unroll)
        if (s < 12) {
            const int sp = s + 4;
            const float* p = (sp < 8) ? (prow_a + sp * 32)
                                      : (prow_b + (sp - 8) * 32);
            xr[s & 3][0] = *(const f32x4*)(p);
            xr[s & 3][1] = *(const f32x4*)(p + 4);
        }

        bf16x8 af;
        af[0] = (__bf16)x0[0]; af[1] = (__bf16)x0[1];
        af[2] = (__bf16)x0[2]; af[3] = (__bf16)x0[3];
        af[4] = (__bf16)x1[0]; af[5] = (__bf16)x1[1];
        af[6] = (__bf16)x1[2]; af[7] = (__bf16)x1[3];

        // conflict-free lane-ordered weight fragments
        const __bf16* wb0 = &wlds[(s * 4 + 0) * 512 + lane * 8];
        bf16x8 w0 = *(const bf16x8*)(wb0);          // cols  0-15
        bf16x8 w1 = *(const bf16x8*)(wb0 + 512);    // cols 16-31
        bf16x8 w2 = *(const bf16x8*)(wb0 + 1024);   // cols 32-47
        bf16x8 w3 = *(const bf16x8*)(wb0 + 1536);   // cols 48-63

        acc0 = __builtin_amdgcn_mfma_f32_16x16x32_bf16(af, w0, acc0, 0, 0, 0);
        acc1 = __builtin_amdgcn_mfma_f32_16x16x32_bf16(af, w1, acc1, 0, 0, 0);
        acc2 = __builtin_amdgcn_mfma_f32_16x16x32_bf16(af, w2, acc2, 0, 0, 0);
        acc3 = __builtin_amdgcn_mfma_f32_16x16x32_bf16(af, w3, acc3, 0, 0, 0);
    }

    // C/D layout: n = lane&15 (+cb*16), m = kg*4 + reg
    float* po = out + (size_t)(tile + kg * 4) * 64 + row;
    #pragma unroll
    for (int r = 0; r < 4; ++r) {
        po[r * 64 +  0] = acc0[r];
        po[r * 64 + 16] = acc1[r];
        po[r * 64 + 32] = acc2[r];
        po[r * 64 + 48] = acc3[r];
    }
}

extern "C" void kernel_launch(void* const* d_in, const int* in_sizes, int n_in,
                              void* d_out, int out_size, void* d_ws, size_t ws_size,
                              hipStream_t stream) {
    const float* xa = (const float*)d_in[0];
    const float* xb = (const float*)d_in[1];
    const float* wa = (const float*)d_in[2];
    const float* wb = (const float*)d_in[3];
    float* out = (float*)d_out;

    if (ws_size >= (size_t)WT_BYTES) {
        __bf16* wt = (__bf16*)d_ws;
        prep_wt_kernel<<<64, 256, 0, stream>>>(wa, wb, wt);
        agg_gemm_kernel<true><<<512, 512, 0, stream>>>(xa, xb, wa, wb, wt, out);
    } else {
        agg_gemm_kernel<false><<<512, 512, 0, stream>>>(xa, xb, wa, wb, nullptr, out);
    }
}